// Round 12
// baseline (212.445 us; speedup 1.0000x reference)
//
#include <hip/hip_runtime.h>
#include <hip/hip_bf16.h>
#include <math.h>

// ==== DIAGNOSTIC: k3 body x8 (idempotent). k1/k4 = R9 verbatim, k2 widened.
// Purpose: k3 dispatch (~8x24us) outruns the ~155us harness fills and claims
// the top-5 rocprof rows -> first real counters for k3. Output bit-identical.
#define REP_K3 8

#define TT 4096
#define BB 32
#define HH 512
#define CC 32000
#define NCHUNK 64   // t-chunks (TT/TPC)
#define TPC 64      // t per chunk (4 waves x 16 rows)
#define HQ 4        // h-quarters in k3
#define OSLICE (BB*CC)  // 1,024,000
#define OW_PAD 36   // LDS row stride (floats); /4 odd => conflict-free b128

// ws layout (float offsets)
#define WS_CTX    0          // 16384 floats (k2->k3)
#define WS_LPART  16384      // 2048 floats (k1->k2)
#define WS_BIG    18432      // cpart 1,048,576 f (k1->k2); then opart 4*1,024,000 f (k3->k4)

__device__ __forceinline__ float dot4(const float4 a, const float4 b) {
  return fmaf(a.w, b.w, fmaf(a.z, b.z, fmaf(a.y, b.y, fmaf(a.x, b.x, 0.f))));
}

// ---------------- k1: fused score + weighted partial sums ------------------
// (R6 verbatim -- measured ~33us, near its HBM/L3 floor. Do not touch.)
__global__ __launch_bounds__(256) void k1_partials(
    const float* __restrict__ dec, const float* __restrict__ aw,
    const float* __restrict__ abp,
    float* __restrict__ ctx_part, float* __restrict__ l_part)
{
  const int chunk = blockIdx.x;
  const int b     = blockIdx.y;
  const int tid   = threadIdx.x;
  const int wv = tid >> 6, ln = tid & 63;
  const float ab = abp[0];
  const float4 aw0 = *(const float4*)(aw + ln*4);          // h in [0,256)
  const float4 aw1 = *(const float4*)(aw + 256 + ln*4);    // h in [256,512)

  const size_t rowstep = (size_t)BB*HH;
  const float* base = dec + ((size_t)(chunk*TPC + wv*16)*BB + b)*HH + (size_t)ln*4;

  float4 c0 = make_float4(0.f,0.f,0.f,0.f), c1 = make_float4(0.f,0.f,0.f,0.f);
  float l = 0.f;

  for (int it = 0; it < 16; it += 2) {
    const float* p0 = base + (size_t)it*rowstep;
    const float* p1 = base + (size_t)(it+1)*rowstep;
    const float4 xa0 = *(const float4*)(p0);
    const float4 xa1 = *(const float4*)(p0 + 256);
    const float4 xb0 = *(const float4*)(p1);
    const float4 xb1 = *(const float4*)(p1 + 256);
    float da = dot4(xa0, aw0) + dot4(xa1, aw1);
    float db = dot4(xb0, aw0) + dot4(xb1, aw1);
    #pragma unroll
    for (int off = 32; off > 0; off >>= 1) {
      da += __shfl_xor(da, off);
      db += __shfl_xor(db, off);
    }
    const float exa = __expf(2.f*(da + ab));
    const float exb = __expf(2.f*(db + ab));
    const float tha = 1.f - 2.f*__builtin_amdgcn_rcpf(exa + 1.f);
    const float thb = 1.f - 2.f*__builtin_amdgcn_rcpf(exb + 1.f);
    const float wa = __expf(tha);
    const float wb = __expf(thb);
    l += wa + wb;
    c0.x = fmaf(wa, xa0.x, fmaf(wb, xb0.x, c0.x));
    c0.y = fmaf(wa, xa0.y, fmaf(wb, xb0.y, c0.y));
    c0.z = fmaf(wa, xa0.z, fmaf(wb, xb0.z, c0.z));
    c0.w = fmaf(wa, xa0.w, fmaf(wb, xb0.w, c0.w));
    c1.x = fmaf(wa, xa1.x, fmaf(wb, xb1.x, c1.x));
    c1.y = fmaf(wa, xa1.y, fmaf(wb, xb1.y, c1.y));
    c1.z = fmaf(wa, xa1.z, fmaf(wb, xb1.z, c1.z));
    c1.w = fmaf(wa, xa1.w, fmaf(wb, xb1.w, c1.w));
  }

  __shared__ float s_ctx[4][HH];
  __shared__ float s_l[4];
  *(float4*)&s_ctx[wv][ln*4]       = c0;
  *(float4*)&s_ctx[wv][256 + ln*4] = c1;
  if (ln == 0) s_l[wv] = l;
  __syncthreads();
  if (tid < 128) {
    const int h = tid * 4;
    float4 a = make_float4(0.f,0.f,0.f,0.f);
    #pragma unroll
    for (int w2 = 0; w2 < 4; ++w2) {
      const float4 v = *(const float4*)&s_ctx[w2][h];
      a.x += v.x; a.y += v.y; a.z += v.z; a.w += v.w;
    }
    const size_t pp = (size_t)b*NCHUNK + chunk;
    *(float4*)(ctx_part + pp*HH + h) = a;
    if (tid == 0) l_part[pp] = s_l[0] + s_l[1] + s_l[2] + s_l[3];
  }
}

// ---------------- k2: combine partials -> normalized context ----------------
// 256 thr: chunk-halves summed in parallel, combined via LDS.
__global__ __launch_bounds__(256) void k2_combine(
    const float* __restrict__ ctx_part, const float* __restrict__ l_part,
    float* __restrict__ ctx)
{
  const int b = blockIdx.x;
  const int tid = threadIdx.x;
  const int half = tid >> 7, hf = tid & 127;
  const int h = hf * 4;

  float4 a = make_float4(0.f,0.f,0.f,0.f);
  const float* basep = ctx_part + ((size_t)b*NCHUNK + half*32)*HH + h;
  #pragma unroll 8
  for (int p = 0; p < 32; ++p) {
    const float4 v = *(const float4*)(basep + (size_t)p*HH);
    a.x += v.x; a.y += v.y; a.z += v.z; a.w += v.w;
  }

  __shared__ float4 s_part[2][128];
  __shared__ float s_L;
  s_part[half][hf] = a;
  if (tid < 64) {
    float Lv = l_part[b*NCHUNK + tid];
    #pragma unroll
    for (int off = 32; off > 0; off >>= 1) Lv += __shfl_xor(Lv, off);
    if (tid == 0) s_L = Lv;
  }
  __syncthreads();
  if (tid < 128) {
    const float4 r0 = s_part[0][tid];
    const float4 r1 = s_part[1][tid];
    const float inv = 1.f / s_L;
    *(float4*)(ctx + (size_t)b*HH + tid*4) = make_float4(
        (r0.x+r1.x)*inv, (r0.y+r1.y)*inv, (r0.z+r1.z)*inv, (r0.w+r1.w)*inv);
  }
}

// ---------------- k3: R9 LDS-tiled GEMM, body x REP_K3 ----------------------
__global__ __launch_bounds__(256) void k3_matmul(
    const float* __restrict__ ctx, const float* __restrict__ ow,
    float* __restrict__ out_part)
{
  __shared__ float s_ow[256*OW_PAD];   // 36.9 KB
  __shared__ float s_cx[32*128];       // 16 KB
  const int tid = threadIdx.x;
  const int ci = tid & 63, wv = tid >> 6;
  const int hq = blockIdx.x, cblk = blockIdx.y;
  const int h0 = hq * 128;
  const int crow0 = cblk * 256;

  for (int rep = 0; rep < REP_K3; ++rep) {
    if (rep) __syncthreads();          // protect s_cx/s_ow across reps
    // stage ctx[:, h0:h0+128] (coalesced; 4 f4 per thread)
    #pragma unroll
    for (int r2 = 0; r2 < 4; ++r2) {
      const int j = r2*1024 + tid*4;
      const int b = j >> 7, hh = j & 127;
      *(float4*)&s_cx[j] = *(const float4*)(ctx + (size_t)b*HH + h0 + hh);
    }

    float acc[4][8];
    #pragma unroll
    for (int g = 0; g < 4; ++g)
      #pragma unroll
      for (int bi = 0; bi < 8; ++bi) acc[g][bi] = 0.f;

    for (int ch = 0; ch < 4; ++ch) {
      if (ch) __syncthreads();         // protect s_ow reads of prev chunk
      // stage ow chunk [256 rows][32 h]: 8 f4/thread, contiguous 128B runs
      #pragma unroll
      for (int r2 = 0; r2 < 8; ++r2) {
        const int j = r2*256 + tid;
        const int r = j >> 3, hp = j & 7;
        *(float4*)&s_ow[r*OW_PAD + hp*4] =
            *(const float4*)(ow + (size_t)(crow0 + r)*HH + h0 + ch*32 + hp*4);
      }
      __syncthreads();
      // compute: 8 h-steps x (4 ow b128 + 8 ctx broadcast b128 + 128 FMA)
      #pragma unroll
      for (int s = 0; s < 8; ++s) {
        float4 w4[4];
        #pragma unroll
        for (int g = 0; g < 4; ++g)
          w4[g] = *(const float4*)&s_ow[(g*64 + ci)*OW_PAD + s*4];
        #pragma unroll
        for (int bi = 0; bi < 8; ++bi) {
          const float4 c4 = *(const float4*)&s_cx[(wv*8 + bi)*128 + ch*32 + s*4];
          #pragma unroll
          for (int g = 0; g < 4; ++g) {
            acc[g][bi] = fmaf(w4[g].w, c4.w, fmaf(w4[g].z, c4.z,
                         fmaf(w4[g].y, c4.y, fmaf(w4[g].x, c4.x, acc[g][bi]))));
          }
        }
      }
    }

    // store: b = wv*8+bi, c = crow0 + g*64 + ci (coalesced; idempotent)
    float* op = out_part + (size_t)hq*OSLICE;
    #pragma unroll
    for (int bi = 0; bi < 8; ++bi) {
      #pragma unroll
      for (int g = 0; g < 4; ++g)
        op[(size_t)(wv*8 + bi)*CC + crow0 + g*64 + ci] = acc[g][bi];
    }
  }
}

// ---------------- k4: sum 4 slices + bias -> d_out --------------------------
__global__ __launch_bounds__(256) void k4_final(
    const float* __restrict__ out_part, const float* __restrict__ ob,
    float* __restrict__ out)
{
  const size_t i = ((size_t)blockIdx.x * 256 + threadIdx.x) * 4;
  float4 r = *(const float4*)(out_part + i);
  #pragma unroll
  for (int q = 1; q < HQ; ++q) {
    const float4 p = *(const float4*)(out_part + (size_t)q*OSLICE + i);
    r.x += p.x; r.y += p.y; r.z += p.z; r.w += p.w;
  }
  const int cIdx = (int)(i % CC);
  const float4 b4 = *(const float4*)(ob + cIdx);
  *(float4*)(out + i) = make_float4(r.x+b4.x, r.y+b4.y, r.z+b4.z, r.w+b4.w);
}

extern "C" void kernel_launch(void* const* d_in, const int* in_sizes, int n_in,
                              void* d_out, int out_size, void* d_ws, size_t ws_size,
                              hipStream_t stream) {
  const float* dec = (const float*)d_in[0];
  const float* aw  = (const float*)d_in[1];
  const float* ab  = (const float*)d_in[2];
  const float* ow  = (const float*)d_in[3];
  const float* ob  = (const float*)d_in[4];
  float* out = (float*)d_out;
  float* ws  = (float*)d_ws;
  float* ctx   = ws + WS_CTX;
  float* lpart = ws + WS_LPART;
  float* big   = ws + WS_BIG;   // cpart for k1/k2, reused as opart for k3/k4

  k1_partials<<<dim3(NCHUNK, BB), 256, 0, stream>>>(dec, aw, ab, big, lpart);
  k2_combine<<<dim3(BB), 256, 0, stream>>>(big, lpart, ctx);
  k3_matmul<<<dim3(HQ, 125), 256, 0, stream>>>(ctx, ow, big);
  k4_final<<<dim3((BB*CC)/(256*4)), 256, 0, stream>>>(big, ob, out);
}

// Round 13
// 90.755 us; speedup vs baseline: 2.3409x; 2.3409x over previous
//
#include <hip/hip_runtime.h>
#include <hip/hip_bf16.h>
#include <math.h>

#define TT 4096
#define BB 32
#define HH 512
#define CC 32000
#define NCHUNK 64   // t-chunks (TT/TPC)
#define TPC 64      // t per chunk (4 waves x 16 rows)
#define HQ 4        // h-quarters in k3
#define K3_TC 128   // c-rows per k3 block (was 256): LDS 34.8KB -> 4 blocks/CU
#define OSLICE (BB*CC)  // 1,024,000
#define OW_PAD 36   // LDS row stride (floats); /4 odd => conflict-free b128

// ws layout (float offsets)
#define WS_CTX    0          // 16384 floats (k2->k3)
#define WS_LPART  16384      // 2048 floats (k1->k2)
#define WS_BIG    18432      // cpart 1,048,576 f (k1->k2); then opart 4*1,024,000 f (k3->k4)

__device__ __forceinline__ float dot4(const float4 a, const float4 b) {
  return fmaf(a.w, b.w, fmaf(a.z, b.z, fmaf(a.y, b.y, fmaf(a.x, b.x, 0.f))));
}

// ---------------- k1: fused score + weighted partial sums ------------------
// (R6 verbatim -- measured ~33us, near its HBM/L3 floor. Do not touch.)
__global__ __launch_bounds__(256) void k1_partials(
    const float* __restrict__ dec, const float* __restrict__ aw,
    const float* __restrict__ abp,
    float* __restrict__ ctx_part, float* __restrict__ l_part)
{
  const int chunk = blockIdx.x;
  const int b     = blockIdx.y;
  const int tid   = threadIdx.x;
  const int wv = tid >> 6, ln = tid & 63;
  const float ab = abp[0];
  const float4 aw0 = *(const float4*)(aw + ln*4);          // h in [0,256)
  const float4 aw1 = *(const float4*)(aw + 256 + ln*4);    // h in [256,512)

  const size_t rowstep = (size_t)BB*HH;
  const float* base = dec + ((size_t)(chunk*TPC + wv*16)*BB + b)*HH + (size_t)ln*4;

  float4 c0 = make_float4(0.f,0.f,0.f,0.f), c1 = make_float4(0.f,0.f,0.f,0.f);
  float l = 0.f;

  for (int it = 0; it < 16; it += 2) {
    const float* p0 = base + (size_t)it*rowstep;
    const float* p1 = base + (size_t)(it+1)*rowstep;
    const float4 xa0 = *(const float4*)(p0);
    const float4 xa1 = *(const float4*)(p0 + 256);
    const float4 xb0 = *(const float4*)(p1);
    const float4 xb1 = *(const float4*)(p1 + 256);
    float da = dot4(xa0, aw0) + dot4(xa1, aw1);
    float db = dot4(xb0, aw0) + dot4(xb1, aw1);
    #pragma unroll
    for (int off = 32; off > 0; off >>= 1) {
      da += __shfl_xor(da, off);
      db += __shfl_xor(db, off);
    }
    const float exa = __expf(2.f*(da + ab));
    const float exb = __expf(2.f*(db + ab));
    const float tha = 1.f - 2.f*__builtin_amdgcn_rcpf(exa + 1.f);
    const float thb = 1.f - 2.f*__builtin_amdgcn_rcpf(exb + 1.f);
    const float wa = __expf(tha);
    const float wb = __expf(thb);
    l += wa + wb;
    c0.x = fmaf(wa, xa0.x, fmaf(wb, xb0.x, c0.x));
    c0.y = fmaf(wa, xa0.y, fmaf(wb, xb0.y, c0.y));
    c0.z = fmaf(wa, xa0.z, fmaf(wb, xb0.z, c0.z));
    c0.w = fmaf(wa, xa0.w, fmaf(wb, xb0.w, c0.w));
    c1.x = fmaf(wa, xa1.x, fmaf(wb, xb1.x, c1.x));
    c1.y = fmaf(wa, xa1.y, fmaf(wb, xb1.y, c1.y));
    c1.z = fmaf(wa, xa1.z, fmaf(wb, xb1.z, c1.z));
    c1.w = fmaf(wa, xa1.w, fmaf(wb, xb1.w, c1.w));
  }

  __shared__ float s_ctx[4][HH];
  __shared__ float s_l[4];
  *(float4*)&s_ctx[wv][ln*4]       = c0;
  *(float4*)&s_ctx[wv][256 + ln*4] = c1;
  if (ln == 0) s_l[wv] = l;
  __syncthreads();
  if (tid < 128) {
    const int h = tid * 4;
    float4 a = make_float4(0.f,0.f,0.f,0.f);
    #pragma unroll
    for (int w2 = 0; w2 < 4; ++w2) {
      const float4 v = *(const float4*)&s_ctx[w2][h];
      a.x += v.x; a.y += v.y; a.z += v.z; a.w += v.w;
    }
    const size_t pp = (size_t)b*NCHUNK + chunk;
    *(float4*)(ctx_part + pp*HH + h) = a;
    if (tid == 0) l_part[pp] = s_l[0] + s_l[1] + s_l[2] + s_l[3];
  }
}

// ---------------- k2: combine partials -> normalized context ----------------
__global__ __launch_bounds__(256) void k2_combine(
    const float* __restrict__ ctx_part, const float* __restrict__ l_part,
    float* __restrict__ ctx)
{
  const int b = blockIdx.x;
  const int tid = threadIdx.x;
  const int half = tid >> 7, hf = tid & 127;
  const int h = hf * 4;

  float4 a = make_float4(0.f,0.f,0.f,0.f);
  const float* basep = ctx_part + ((size_t)b*NCHUNK + half*32)*HH + h;
  #pragma unroll 8
  for (int p = 0; p < 32; ++p) {
    const float4 v = *(const float4*)(basep + (size_t)p*HH);
    a.x += v.x; a.y += v.y; a.z += v.z; a.w += v.w;
  }

  __shared__ float4 s_part[2][128];
  __shared__ float s_L;
  s_part[half][hf] = a;
  if (tid < 64) {
    float Lv = l_part[b*NCHUNK + tid];
    #pragma unroll
    for (int off = 32; off > 0; off >>= 1) Lv += __shfl_xor(Lv, off);
    if (tid == 0) s_L = Lv;
  }
  __syncthreads();
  if (tid < 128) {
    const float4 r0 = s_part[0][tid];
    const float4 r1 = s_part[1][tid];
    const float inv = 1.f / s_L;
    *(float4*)(ctx + (size_t)b*HH + tid*4) = make_float4(
        (r0.x+r1.x)*inv, (r0.y+r1.y)*inv, (r0.z+r1.z)*inv, (r0.w+r1.w)*inv);
  }
}

// ---------------- k3: LDS-tiled GEMM, 128c tile, 4 blocks/CU ----------------
// R12 instrument: k3 is COLD every replay (k1's 256MB dec stream evicts ow
// from L3) -> 47us at ~1.4 TB/s. Cause: barrier-lockstep staging with only
// 2 blocks/CU -> fetch never overlaps compute. Fix: 128c x 128h tile, LDS
// 34.8KB -> 4 blocks/CU (grid 1000, 16 waves/CU): four unsynchronized block
// phases per CU keep the HBM queue fed while others compute.
__global__ __launch_bounds__(256) void k3_matmul(
    const float* __restrict__ ctx, const float* __restrict__ ow,
    float* __restrict__ out_part)
{
  __shared__ float s_ow[K3_TC*OW_PAD];  // 18.4 KB
  __shared__ float s_cx[32*128];        // 16 KB
  const int tid = threadIdx.x;
  const int ci = tid & 63, wv = tid >> 6;
  const int cblk = blockIdx.x, hq = blockIdx.y;
  const int h0 = hq * 128;
  const int crow0 = cblk * K3_TC;

  // stage ctx[:, h0:h0+128] once (coalesced; 4 f4 per thread)
  #pragma unroll
  for (int rep = 0; rep < 4; ++rep) {
    const int j = rep*1024 + tid*4;
    const int b = j >> 7, hh = j & 127;
    *(float4*)&s_cx[j] = *(const float4*)(ctx + (size_t)b*HH + h0 + hh);
  }

  float acc[2][8];
  #pragma unroll
  for (int g = 0; g < 2; ++g)
    #pragma unroll
    for (int bi = 0; bi < 8; ++bi) acc[g][bi] = 0.f;

  for (int ch = 0; ch < 4; ++ch) {
    if (ch) __syncthreads();           // protect s_ow reads of prev chunk
    // stage ow chunk [128 rows][32 h]: 4 f4/thread, contiguous 128B runs
    #pragma unroll
    for (int r2 = 0; r2 < 4; ++r2) {
      const int j = r2*256 + tid;
      const int r = j >> 3, hp = j & 7;
      *(float4*)&s_ow[r*OW_PAD + hp*4] =
          *(const float4*)(ow + (size_t)(crow0 + r)*HH + h0 + ch*32 + hp*4);
    }
    __syncthreads();                   // also covers s_cx on ch==0
    // compute: 8 h-steps x (2 ow b128 + 8 ctx broadcast b128 + 64 FMA)
    #pragma unroll
    for (int s = 0; s < 8; ++s) {
      float4 w4[2];
      #pragma unroll
      for (int g = 0; g < 2; ++g)
        w4[g] = *(const float4*)&s_ow[(g*64 + ci)*OW_PAD + s*4];
      #pragma unroll
      for (int bi = 0; bi < 8; ++bi) {
        const float4 c4 = *(const float4*)&s_cx[(wv*8 + bi)*128 + ch*32 + s*4];
        #pragma unroll
        for (int g = 0; g < 2; ++g) {
          acc[g][bi] = fmaf(w4[g].w, c4.w, fmaf(w4[g].z, c4.z,
                       fmaf(w4[g].y, c4.y, fmaf(w4[g].x, c4.x, acc[g][bi]))));
        }
      }
    }
  }

  // store: b = wv*8+bi, c = crow0 + g*64 + ci (coalesced 256B per instr)
  float* op = out_part + (size_t)hq*OSLICE;
  #pragma unroll
  for (int bi = 0; bi < 8; ++bi) {
    #pragma unroll
    for (int g = 0; g < 2; ++g)
      op[(size_t)(wv*8 + bi)*CC + crow0 + g*64 + ci] = acc[g][bi];
  }
}

// ---------------- k4: sum 4 slices + bias -> d_out --------------------------
__global__ __launch_bounds__(256) void k4_final(
    const float* __restrict__ out_part, const float* __restrict__ ob,
    float* __restrict__ out)
{
  const size_t i = ((size_t)blockIdx.x * 256 + threadIdx.x) * 4;
  float4 r = *(const float4*)(out_part + i);
  #pragma unroll
  for (int q = 1; q < HQ; ++q) {
    const float4 p = *(const float4*)(out_part + (size_t)q*OSLICE + i);
    r.x += p.x; r.y += p.y; r.z += p.z; r.w += p.w;
  }
  const int cIdx = (int)(i % CC);
  const float4 b4 = *(const float4*)(ob + cIdx);
  *(float4*)(out + i) = make_float4(r.x+b4.x, r.y+b4.y, r.z+b4.z, r.w+b4.w);
}

extern "C" void kernel_launch(void* const* d_in, const int* in_sizes, int n_in,
                              void* d_out, int out_size, void* d_ws, size_t ws_size,
                              hipStream_t stream) {
  const float* dec = (const float*)d_in[0];
  const float* aw  = (const float*)d_in[1];
  const float* ab  = (const float*)d_in[2];
  const float* ow  = (const float*)d_in[3];
  const float* ob  = (const float*)d_in[4];
  float* out = (float*)d_out;
  float* ws  = (float*)d_ws;
  float* ctx   = ws + WS_CTX;
  float* lpart = ws + WS_LPART;
  float* big   = ws + WS_BIG;   // cpart for k1/k2, reused as opart for k3/k4

  k1_partials<<<dim3(NCHUNK, BB), 256, 0, stream>>>(dec, aw, ab, big, lpart);
  k2_combine<<<dim3(BB), 256, 0, stream>>>(big, lpart, ctx);
  k3_matmul<<<dim3(CC/K3_TC, HQ), 256, 0, stream>>>(ctx, ow, big);
  k4_final<<<dim3((BB*CC)/(256*4)), 256, 0, stream>>>(big, ob, out);
}